// Round 12
// baseline (61.511 us; speedup 1.0000x reference)
//
#include <hip/hip_runtime.h>

// NanoDet GFL loss (QFL + GIoU + DFL), single f32 scalar output.
// R12 = R11 + single-dispatch merge via FENCE-FREE last-block-done:
//   - per-block partials published with RELAXED agent-scope atomic stores
//     (coherence-point write-through; no buffer_wbl2),
//   - ordered by hardware `s_waitcnt vmcnt(0)` (store completion), NOT a
//     C++ release fence (R6's threadfence x2048 = L2 wb/inv storm, 169us),
//   - RELAXED agent fetch_add ticket; winner reads partials with relaxed
//     agent loads (bypass stale L2) and does the fixed-order reduction.
// Counter zeroed per call by a captured 4-byte hipMemsetAsync (stateless).
//   phase 1: streaming neg-QFL over cls_score (145 MB, f32x4, 8-deep,
//            4 independent packed accumulators; 3 trans/logit ~= mem time).
//   phase 2: per-row sparse terms, <=1 row/thread, exec-masked, one
//            independent-load latency batch (lab/lw prefetched).

namespace {
constexpr int   kNumClasses = 80;
constexpr int   kF4PerRow   = kNumClasses / 4;   // 20
constexpr float kEps        = 1e-6f;
constexpr int   kThreads    = 256;
constexpr int   kMaxBlocks  = 2048;
constexpr float kLog2E      = 1.4426950408889634f;
constexpr float kLn2        = 0.6931471805599453f;
}

typedef __attribute__((ext_vector_type(2))) float f32x2;
typedef __attribute__((ext_vector_type(4))) float f32x4;

__device__ __forceinline__ float fexp2(float x) { return __builtin_amdgcn_exp2f(x); }
__device__ __forceinline__ float flog2(float x) { return __builtin_amdgcn_logf(x); }
__device__ __forceinline__ float frcp(float x)  { return __builtin_amdgcn_rcpf(x); }

__device__ __forceinline__ float wave_reduce_sum(float v) {
#pragma unroll
  for (int off = 32; off > 0; off >>= 1) v += __shfl_down(v, off, 64);
  return v;
}

// Unweighted negative-QFL pair, in log2 units (caller multiplies by ln2):
//   z = e^x; u = 1+z; sig = z/u; returns log2(u) * sig^2 per component.
__device__ __forceinline__ f32x2 neg_t2(f32x2 x) {
  f32x2 t = x * (f32x2)kLog2E;                      // v_pk_mul
  t = __builtin_elementwise_min(t, (f32x2)86.0f);   // overflow guard
  f32x2 z; z.x = fexp2(t.x); z.y = fexp2(t.y);
  const f32x2 u = z + (f32x2)1.0f;                  // v_pk_add
  f32x2 r; r.x = frcp(u.x); r.y = frcp(u.y);
  f32x2 l; l.x = flog2(u.x); l.y = flog2(u.y);
  const f32x2 sig = z * r;                          // v_pk_mul
  return l * sig * sig;                             // 2x v_pk_mul
}

__device__ __forceinline__ f32x2 neg_v4(f32x4 v) {
  f32x2 a; a.x = v.x; a.y = v.y;
  f32x2 b; b.x = v.z; b.y = v.w;
  return neg_t2(a) + neg_t2(b);
}

__device__ __forceinline__ void pos_row_body(
    int n, int lab, float lw,
    const float* __restrict__ cls_score,
    const float* __restrict__ bbox_pred,
    const float* __restrict__ anchors,
    const float* __restrict__ bbox_targets,
    const float* __restrict__ strides,
    float& s_corr, float& s_bbox, float& s_dfl, float& s_wt, float& s_pos)
{
  const bool pos = (unsigned)lab < (unsigned)kNumClasses;
  const bool lwodd = (lw != 1.0f);
  if (!pos && !lwodd) return;  // execz-skips ~95% of lanes

  const float* cr = cls_score + (size_t)n * kNumClasses;
  const f32x4* cr4 = reinterpret_cast<const f32x4*>(cr);

  if (lwodd) {  // never taken for this input; correct for any input
    f32x2 rs = (f32x2)0.0f;
#pragma unroll
    for (int i = 0; i < kF4PerRow; ++i) rs += neg_v4(cr4[i]);
    s_corr = __builtin_fmaf(lw - 1.0f, kLn2 * (rs.x + rs.y), s_corr);
  }

  if (!pos) return;

  const float inv_s = frcp(strides[n]);

  const f32x4 anc = reinterpret_cast<const f32x4*>(anchors)[n];
  const float cx = (anc.x + anc.z) * 0.5f * inv_s;
  const float cy = (anc.y + anc.w) * 0.5f * inv_s;

  const f32x4 tg = reinterpret_cast<const f32x4*>(bbox_targets)[n];
  const float tx0 = tg.x * inv_s, ty0 = tg.y * inv_s;
  const float tx1 = tg.z * inv_s, ty1 = tg.w * inv_s;

  // row max of logits (max sigmoid == sigmoid(max logit))
  float rm = -3.4e38f;
#pragma unroll
  for (int i = 0; i < kF4PerRow; ++i) {
    const f32x4 v = cr4[i];
    rm = fmaxf(rm, fmaxf(fmaxf(v.x, v.y), fmaxf(v.z, v.w)));
  }
  const float em  = fexp2(-fabsf(rm) * kLog2E);
  const float rmr = frcp(1.f + em);
  const float max_sig = (rm >= 0.f) ? rmr : 1.f - rmr;  // == wt

  // fused Integral softmax + DFL per side
  const float dist[4] = {cx - tx0, cy - ty0, tx1 - cx, ty1 - cy};
  float corners[4];
  float dfl = 0.f;
  const float* bp = bbox_pred + (size_t)n * 32;
#pragma unroll
  for (int k = 0; k < 4; ++k) {
    const f32x4 v0 = reinterpret_cast<const f32x4*>(bp)[k * 2 + 0];
    const f32x4 v1 = reinterpret_cast<const f32x4*>(bp)[k * 2 + 1];
    const float xk[8] = {v0.x, v0.y, v0.z, v0.w, v1.x, v1.y, v1.z, v1.w};
    float m = xk[0];
#pragma unroll
    for (int b = 1; b < 8; ++b) m = fmaxf(m, xk[b]);
    const float m2 = m * kLog2E;
    const float d  = fminf(fmaxf(dist[k], 0.f), 6.99f);
    float Z = 0.f, E = 0.f, W = 0.f;
#pragma unroll
    for (int b = 0; b < 8; ++b) {
      const float e = fexp2(__builtin_fmaf(xk[b], kLog2E, -m2));
      Z += e;
      E = __builtin_fmaf((float)b, e, E);
      const float w = fmaxf(1.f - fabsf(d - (float)b), 0.f);
      W = __builtin_fmaf(w, xk[b], W);
    }
    corners[k] = E * frcp(Z);
    dfl += __builtin_fmaf(kLn2, flog2(Z), m) - W;  // logZ_k - W_k
  }

  const float px0 = cx - corners[0], py0 = cy - corners[1];
  const float px1 = cx + corners[2], py1 = cy + corners[3];

  const float ov_w = fmaxf(fminf(px1, tx1) - fmaxf(px0, tx0), 0.f);
  const float ov_h = fmaxf(fminf(py1, ty1) - fmaxf(py0, ty0), 0.f);
  const float overlap = ov_w * ov_h;
  const float area_p = fmaxf(px1 - px0, 0.f) * fmaxf(py1 - py0, 0.f);
  const float area_t = fmaxf(tx1 - tx0, 0.f) * fmaxf(ty1 - ty0, 0.f);
  const float uni = area_p + area_t - overlap;
  const float score = overlap * frcp(fmaxf(uni, kEps));  // aligned IoU

  const float uni_g = fmaxf(uni, kEps);
  const float iou_g = overlap * frcp(uni_g);
  const float en_w = fmaxf(fmaxf(px1, tx1) - fminf(px0, tx0), 0.f);
  const float en_h = fmaxf(fmaxf(py1, ty1) - fminf(py0, ty0), 0.f);
  const float enclose = fmaxf(en_w * en_h, kEps);
  const float giou = iou_g - (enclose - uni_g) * frcp(enclose);

  // QFL positive correction at class `lab` (stable |x| form)
  const float x    = cr[lab];
  const float e    = fexp2(-fabsf(x) * kLog2E);
  const float u    = 1.f + e;
  const float r    = frcp(u);
  const float sig  = (x >= 0.f) ? r : 1.f - r;
  const float bce0 = fmaxf(x, 0.f) + kLn2 * flog2(u);
  const float dq   = score - sig;
  const float corr = (bce0 - x * score) * dq * dq - bce0 * sig * sig;

  s_corr = __builtin_fmaf(corr, lw, s_corr);
  s_bbox = __builtin_fmaf(1.f - giou, max_sig, s_bbox);
  s_dfl  = __builtin_fmaf(dfl, max_sig, s_dfl);
  s_wt  += max_sig;
  s_pos += 1.f;
}

__global__ __launch_bounds__(kThreads) void nanodet_fused(
    const float* __restrict__ cls_score,     // [N,80]
    const float* __restrict__ bbox_pred,     // [N,32]
    const float* __restrict__ anchors,       // [N,4]
    const float* __restrict__ bbox_targets,  // [N,4]
    const float* __restrict__ label_weights, // [N]
    const float* __restrict__ strides,       // [N]
    const int*   __restrict__ labels,        // [N]
    float*       __restrict__ partials,      // [grid][6]
    unsigned*    __restrict__ counter,       // memset 0 per call
    float*       __restrict__ out,
    int N, int M4)
{
  const int tid = threadIdx.x;
  const int bid = blockIdx.x;
  const int nth = gridDim.x * kThreads;
  const int n0  = bid * kThreads + tid;

  // Prefetch row predicate data (coalesced) before the stream.
  const int   lab0 = (n0 < N) ? labels[n0] : kNumClasses;
  const float lw0  = (n0 < N) ? label_weights[n0] : 1.0f;

  // ---------------- phase 1: streaming neg-QFL over all logits ----------
  float s_neg;
  {
    const f32x4* cs = reinterpret_cast<const f32x4*>(cls_score);
    f32x2 a0 = (f32x2)0.f, a1 = (f32x2)0.f, a2 = (f32x2)0.f, a3 = (f32x2)0.f;
    int i = n0;
    for (; i + 7 * nth < M4; i += 8 * nth) {
      const f32x4 v0 = cs[i];
      const f32x4 v1 = cs[i + nth];
      const f32x4 v2 = cs[i + 2 * nth];
      const f32x4 v3 = cs[i + 3 * nth];
      const f32x4 v4 = cs[i + 4 * nth];
      const f32x4 v5 = cs[i + 5 * nth];
      const f32x4 v6 = cs[i + 6 * nth];
      const f32x4 v7 = cs[i + 7 * nth];
      a0 += neg_v4(v0); a1 += neg_v4(v1); a2 += neg_v4(v2); a3 += neg_v4(v3);
      a0 += neg_v4(v4); a1 += neg_v4(v5); a2 += neg_v4(v6); a3 += neg_v4(v7);
    }
    for (; i < M4; i += nth) a0 += neg_v4(cs[i]);
    const f32x2 at = (a0 + a1) + (a2 + a3);
    s_neg = kLn2 * (at.x + at.y);
  }

  // ---------------- phase 2: per-row sparse terms ----------------
  float s_corr = 0.f, s_bbox = 0.f, s_dfl = 0.f, s_wt = 0.f, s_pos = 0.f;
  if (n0 < N) {
    pos_row_body(n0, lab0, lw0, cls_score, bbox_pred, anchors, bbox_targets,
                 strides, s_corr, s_bbox, s_dfl, s_wt, s_pos);
  }
  for (int n = n0 + nth; n < N; n += nth) {  // never taken when nth >= N
    pos_row_body(n, labels[n], label_weights[n], cls_score, bbox_pred, anchors,
                 bbox_targets, strides, s_corr, s_bbox, s_dfl, s_wt, s_pos);
  }

  // ---------------- block reduction of 6 sums ----------------
  __shared__ float red[4][6];
  __shared__ unsigned s_last;
  {
    float vals[6] = {s_corr, s_bbox, s_dfl, s_wt, s_pos, s_neg};
    const int lane = tid & 63, wid = tid >> 6;
#pragma unroll
    for (int k = 0; k < 6; ++k) {
      const float r = wave_reduce_sum(vals[k]);
      if (lane == 0) red[wid][k] = r;
    }
  }
  __syncthreads();

  // ---- publish partials: relaxed agent stores + vmcnt(0) + relaxed RMW ----
  // No release fence / threadfence: agent-scope annotated stores go to the
  // coherence point; s_waitcnt vmcnt(0) guarantees completion there before
  // the ticket increment. Avoids R6's per-block L2 wb/inv storm.
  if (tid == 0) {
#pragma unroll
    for (int k = 0; k < 6; ++k) {
      const float bs = red[0][k] + red[1][k] + red[2][k] + red[3][k];
      __hip_atomic_store(&partials[(size_t)bid * 6 + k], bs,
                         __ATOMIC_RELAXED, __HIP_MEMORY_SCOPE_AGENT);
    }
    asm volatile("s_waitcnt vmcnt(0)" ::: "memory");
    const unsigned old = __hip_atomic_fetch_add(
        counter, 1u, __ATOMIC_RELAXED, __HIP_MEMORY_SCOPE_AGENT);
    s_last = (old == (unsigned)gridDim.x - 1u) ? 1u : 0u;
  }
  __syncthreads();

  // ---------------- last block: deterministic fixed-order reduction ------
  if (s_last) {
    float v[6] = {0.f, 0.f, 0.f, 0.f, 0.f, 0.f};
    for (int i = tid; i < (int)gridDim.x; i += kThreads) {
#pragma unroll
      for (int k = 0; k < 6; ++k)
        v[k] += __hip_atomic_load(&partials[(size_t)i * 6 + k],
                                  __ATOMIC_RELAXED, __HIP_MEMORY_SCOPE_AGENT);
    }
    const int lane = tid & 63, wid = tid >> 6;
#pragma unroll
    for (int k = 0; k < 6; ++k) {
      const float r = wave_reduce_sum(v[k]);
      if (lane == 0) red[wid][k] = r;
    }
    __syncthreads();
    if (tid == 0) {
      const float S_corr = red[0][0] + red[1][0] + red[2][0] + red[3][0];
      const float S_bbox = red[0][1] + red[1][1] + red[2][1] + red[3][1];
      const float S_dfl  = red[0][2] + red[1][2] + red[2][2] + red[3][2];
      const float S_wt   = red[0][3] + red[1][3] + red[2][3] + red[3][3];
      const float S_pos  = red[0][4] + red[1][4] + red[2][4] + red[3][4];
      const float S_neg  = red[0][5] + red[1][5] + red[2][5] + red[3][5];
      const float num_pos = fmaxf(S_pos, 1.0f);   // num_total_samples
      const float avg     = fmaxf(S_wt, kEps);    // avg_factor = sum(wt)
      out[0] = (S_neg + S_corr) / num_pos
             + 2.0f * S_bbox / avg + 0.0625f * S_dfl / avg;
    }
  }
}

extern "C" void kernel_launch(void* const* d_in, const int* in_sizes, int n_in,
                              void* d_out, int out_size, void* d_ws, size_t ws_size,
                              hipStream_t stream) {
  const float* cls_score     = (const float*)d_in[0];
  const float* bbox_pred     = (const float*)d_in[1];
  const float* anchors       = (const float*)d_in[2];
  const float* bbox_targets  = (const float*)d_in[3];
  const float* label_weights = (const float*)d_in[4];
  const float* strides       = (const float*)d_in[5];
  const int*   labels        = (const int*)d_in[6];
  const int N  = in_sizes[4];      // label_weights is [N]
  const int M4 = N * kF4PerRow;    // float4 count of cls_score

  float*    partials = (float*)d_ws;                          // [grid][6]
  unsigned* counter  = (unsigned*)((char*)d_ws +
                        (size_t)kMaxBlocks * 6 * sizeof(float));

  int grid = (M4 + kThreads - 1) / kThreads;
  if (grid > kMaxBlocks) grid = kMaxBlocks;
  if (grid < 1) grid = 1;

  hipMemsetAsync(counter, 0, sizeof(unsigned), stream);
  nanodet_fused<<<grid, kThreads, 0, stream>>>(
      cls_score, bbox_pred, anchors, bbox_targets, label_weights, strides,
      labels, partials, counter, (float*)d_out, N, M4);
}

// Round 13
// 51.619 us; speedup vs baseline: 1.1916x; 1.1916x over previous
//
#include <hip/hip_runtime.h>

// NanoDet GFL loss (QFL + GIoU + DFL), single f32 scalar output.
// R13 = R11 body + single-dispatch finish via HIERARCHICAL fence-free arrival:
//   R12 lesson: 2048 same-line agent-scope RMWs serialize at the coherence
//   point (~+15us). Two-level ticket caps same-line contention at 64:
//     32 group counters (64 blocks each, 128-B line apart) + 1 root (32).
//   Publish: relaxed agent stores -> s_waitcnt vmcnt(0) -> relaxed RMW
//   group; group-last RMWs root; root-last block = winner, reduces the
//   fixed-order partials with relaxed agent loads (bypass stale L2).
//   No __threadfence anywhere (R6 lesson: per-block L2 wb/inv storm).
// Counters zeroed per call by one captured hipMemsetAsync (stateless).

namespace {
constexpr int   kNumClasses = 80;
constexpr int   kF4PerRow   = kNumClasses / 4;   // 20
constexpr float kEps        = 1e-6f;
constexpr int   kThreads    = 256;
constexpr int   kMaxBlocks  = 2048;
constexpr int   kGroupShift = 6;                 // 64 blocks per group
constexpr int   kGroupSize  = 1 << kGroupShift;
constexpr int   kMaxGroups  = kMaxBlocks / kGroupSize;  // 32
constexpr int   kCntStride  = 32;                // uints: 128 B between lines
constexpr float kLog2E      = 1.4426950408889634f;
constexpr float kLn2        = 0.6931471805599453f;
}

typedef __attribute__((ext_vector_type(2))) float f32x2;
typedef __attribute__((ext_vector_type(4))) float f32x4;

__device__ __forceinline__ float fexp2(float x) { return __builtin_amdgcn_exp2f(x); }
__device__ __forceinline__ float flog2(float x) { return __builtin_amdgcn_logf(x); }
__device__ __forceinline__ float frcp(float x)  { return __builtin_amdgcn_rcpf(x); }

__device__ __forceinline__ float wave_reduce_sum(float v) {
#pragma unroll
  for (int off = 32; off > 0; off >>= 1) v += __shfl_down(v, off, 64);
  return v;
}

// Unweighted negative-QFL pair, in log2 units (caller multiplies by ln2):
//   z = e^x; u = 1+z; sig = z/u; returns log2(u) * sig^2 per component.
__device__ __forceinline__ f32x2 neg_t2(f32x2 x) {
  f32x2 t = x * (f32x2)kLog2E;                      // v_pk_mul
  t = __builtin_elementwise_min(t, (f32x2)86.0f);   // overflow guard
  f32x2 z; z.x = fexp2(t.x); z.y = fexp2(t.y);
  const f32x2 u = z + (f32x2)1.0f;                  // v_pk_add
  f32x2 r; r.x = frcp(u.x); r.y = frcp(u.y);
  f32x2 l; l.x = flog2(u.x); l.y = flog2(u.y);
  const f32x2 sig = z * r;                          // v_pk_mul
  return l * sig * sig;                             // 2x v_pk_mul
}

__device__ __forceinline__ f32x2 neg_v4(f32x4 v) {
  f32x2 a; a.x = v.x; a.y = v.y;
  f32x2 b; b.x = v.z; b.y = v.w;
  return neg_t2(a) + neg_t2(b);
}

__device__ __forceinline__ void pos_row_body(
    int n, int lab, float lw,
    const float* __restrict__ cls_score,
    const float* __restrict__ bbox_pred,
    const float* __restrict__ anchors,
    const float* __restrict__ bbox_targets,
    const float* __restrict__ strides,
    float& s_corr, float& s_bbox, float& s_dfl, float& s_wt, float& s_pos)
{
  const bool pos = (unsigned)lab < (unsigned)kNumClasses;
  const bool lwodd = (lw != 1.0f);
  if (!pos && !lwodd) return;  // execz-skips ~95% of lanes

  const float* cr = cls_score + (size_t)n * kNumClasses;
  const f32x4* cr4 = reinterpret_cast<const f32x4*>(cr);

  if (lwodd) {  // never taken for this input; correct for any input
    f32x2 rs = (f32x2)0.0f;
#pragma unroll
    for (int i = 0; i < kF4PerRow; ++i) rs += neg_v4(cr4[i]);
    s_corr = __builtin_fmaf(lw - 1.0f, kLn2 * (rs.x + rs.y), s_corr);
  }

  if (!pos) return;

  const float inv_s = frcp(strides[n]);

  const f32x4 anc = reinterpret_cast<const f32x4*>(anchors)[n];
  const float cx = (anc.x + anc.z) * 0.5f * inv_s;
  const float cy = (anc.y + anc.w) * 0.5f * inv_s;

  const f32x4 tg = reinterpret_cast<const f32x4*>(bbox_targets)[n];
  const float tx0 = tg.x * inv_s, ty0 = tg.y * inv_s;
  const float tx1 = tg.z * inv_s, ty1 = tg.w * inv_s;

  // row max of logits (max sigmoid == sigmoid(max logit))
  float rm = -3.4e38f;
#pragma unroll
  for (int i = 0; i < kF4PerRow; ++i) {
    const f32x4 v = cr4[i];
    rm = fmaxf(rm, fmaxf(fmaxf(v.x, v.y), fmaxf(v.z, v.w)));
  }
  const float em  = fexp2(-fabsf(rm) * kLog2E);
  const float rmr = frcp(1.f + em);
  const float max_sig = (rm >= 0.f) ? rmr : 1.f - rmr;  // == wt

  // fused Integral softmax + DFL per side
  const float dist[4] = {cx - tx0, cy - ty0, tx1 - cx, ty1 - cy};
  float corners[4];
  float dfl = 0.f;
  const float* bp = bbox_pred + (size_t)n * 32;
#pragma unroll
  for (int k = 0; k < 4; ++k) {
    const f32x4 v0 = reinterpret_cast<const f32x4*>(bp)[k * 2 + 0];
    const f32x4 v1 = reinterpret_cast<const f32x4*>(bp)[k * 2 + 1];
    const float xk[8] = {v0.x, v0.y, v0.z, v0.w, v1.x, v1.y, v1.z, v1.w};
    float m = xk[0];
#pragma unroll
    for (int b = 1; b < 8; ++b) m = fmaxf(m, xk[b]);
    const float m2 = m * kLog2E;
    const float d  = fminf(fmaxf(dist[k], 0.f), 6.99f);
    float Z = 0.f, E = 0.f, W = 0.f;
#pragma unroll
    for (int b = 0; b < 8; ++b) {
      const float e = fexp2(__builtin_fmaf(xk[b], kLog2E, -m2));
      Z += e;
      E = __builtin_fmaf((float)b, e, E);
      const float w = fmaxf(1.f - fabsf(d - (float)b), 0.f);
      W = __builtin_fmaf(w, xk[b], W);
    }
    corners[k] = E * frcp(Z);
    dfl += __builtin_fmaf(kLn2, flog2(Z), m) - W;  // logZ_k - W_k
  }

  const float px0 = cx - corners[0], py0 = cy - corners[1];
  const float px1 = cx + corners[2], py1 = cy + corners[3];

  const float ov_w = fmaxf(fminf(px1, tx1) - fmaxf(px0, tx0), 0.f);
  const float ov_h = fmaxf(fminf(py1, ty1) - fmaxf(py0, ty0), 0.f);
  const float overlap = ov_w * ov_h;
  const float area_p = fmaxf(px1 - px0, 0.f) * fmaxf(py1 - py0, 0.f);
  const float area_t = fmaxf(tx1 - tx0, 0.f) * fmaxf(ty1 - ty0, 0.f);
  const float uni = area_p + area_t - overlap;
  const float score = overlap * frcp(fmaxf(uni, kEps));  // aligned IoU

  const float uni_g = fmaxf(uni, kEps);
  const float iou_g = overlap * frcp(uni_g);
  const float en_w = fmaxf(fmaxf(px1, tx1) - fminf(px0, tx0), 0.f);
  const float en_h = fmaxf(fmaxf(py1, ty1) - fminf(py0, ty0), 0.f);
  const float enclose = fmaxf(en_w * en_h, kEps);
  const float giou = iou_g - (enclose - uni_g) * frcp(enclose);

  // QFL positive correction at class `lab` (stable |x| form)
  const float x    = cr[lab];
  const float e    = fexp2(-fabsf(x) * kLog2E);
  const float u    = 1.f + e;
  const float r    = frcp(u);
  const float sig  = (x >= 0.f) ? r : 1.f - r;
  const float bce0 = fmaxf(x, 0.f) + kLn2 * flog2(u);
  const float dq   = score - sig;
  const float corr = (bce0 - x * score) * dq * dq - bce0 * sig * sig;

  s_corr = __builtin_fmaf(corr, lw, s_corr);
  s_bbox = __builtin_fmaf(1.f - giou, max_sig, s_bbox);
  s_dfl  = __builtin_fmaf(dfl, max_sig, s_dfl);
  s_wt  += max_sig;
  s_pos += 1.f;
}

__global__ __launch_bounds__(kThreads) void nanodet_fused(
    const float* __restrict__ cls_score,     // [N,80]
    const float* __restrict__ bbox_pred,     // [N,32]
    const float* __restrict__ anchors,       // [N,4]
    const float* __restrict__ bbox_targets,  // [N,4]
    const float* __restrict__ label_weights, // [N]
    const float* __restrict__ strides,       // [N]
    const int*   __restrict__ labels,        // [N]
    float*       __restrict__ partials,      // [grid][6]
    unsigned*    __restrict__ counters,      // [32 groups x 32-stride + root]
    float*       __restrict__ out,
    int N, int M4)
{
  const int tid = threadIdx.x;
  const int bid = blockIdx.x;
  const int nth = gridDim.x * kThreads;
  const int n0  = bid * kThreads + tid;

  // Prefetch row predicate data (coalesced) before the stream.
  const int   lab0 = (n0 < N) ? labels[n0] : kNumClasses;
  const float lw0  = (n0 < N) ? label_weights[n0] : 1.0f;

  // ---------------- phase 1: streaming neg-QFL over all logits ----------
  float s_neg;
  {
    const f32x4* cs = reinterpret_cast<const f32x4*>(cls_score);
    f32x2 a0 = (f32x2)0.f, a1 = (f32x2)0.f, a2 = (f32x2)0.f, a3 = (f32x2)0.f;
    int i = n0;
    for (; i + 7 * nth < M4; i += 8 * nth) {
      const f32x4 v0 = cs[i];
      const f32x4 v1 = cs[i + nth];
      const f32x4 v2 = cs[i + 2 * nth];
      const f32x4 v3 = cs[i + 3 * nth];
      const f32x4 v4 = cs[i + 4 * nth];
      const f32x4 v5 = cs[i + 5 * nth];
      const f32x4 v6 = cs[i + 6 * nth];
      const f32x4 v7 = cs[i + 7 * nth];
      a0 += neg_v4(v0); a1 += neg_v4(v1); a2 += neg_v4(v2); a3 += neg_v4(v3);
      a0 += neg_v4(v4); a1 += neg_v4(v5); a2 += neg_v4(v6); a3 += neg_v4(v7);
    }
    for (; i < M4; i += nth) a0 += neg_v4(cs[i]);
    const f32x2 at = (a0 + a1) + (a2 + a3);
    s_neg = kLn2 * (at.x + at.y);
  }

  // ---------------- phase 2: per-row sparse terms ----------------
  float s_corr = 0.f, s_bbox = 0.f, s_dfl = 0.f, s_wt = 0.f, s_pos = 0.f;
  if (n0 < N) {
    pos_row_body(n0, lab0, lw0, cls_score, bbox_pred, anchors, bbox_targets,
                 strides, s_corr, s_bbox, s_dfl, s_wt, s_pos);
  }
  for (int n = n0 + nth; n < N; n += nth) {  // never taken when nth >= N
    pos_row_body(n, labels[n], label_weights[n], cls_score, bbox_pred, anchors,
                 bbox_targets, strides, s_corr, s_bbox, s_dfl, s_wt, s_pos);
  }

  // ---------------- block reduction of 6 sums ----------------
  __shared__ float red[4][6];
  __shared__ unsigned s_last;
  {
    float vals[6] = {s_corr, s_bbox, s_dfl, s_wt, s_pos, s_neg};
    const int lane = tid & 63, wid = tid >> 6;
#pragma unroll
    for (int k = 0; k < 6; ++k) {
      const float r = wave_reduce_sum(vals[k]);
      if (lane == 0) red[wid][k] = r;
    }
  }
  __syncthreads();

  // ---- publish + hierarchical fence-free arrival (tid 0 only) ----
  if (tid == 0) {
#pragma unroll
    for (int k = 0; k < 6; ++k) {
      const float bs = red[0][k] + red[1][k] + red[2][k] + red[3][k];
      __hip_atomic_store(&partials[(size_t)bid * 6 + k], bs,
                         __ATOMIC_RELAXED, __HIP_MEMORY_SCOPE_AGENT);
    }
    asm volatile("s_waitcnt vmcnt(0)" ::: "memory");  // stores at coherence pt

    const int grid    = (int)gridDim.x;
    const int g       = bid >> kGroupShift;
    const int ngroups = (grid + kGroupSize - 1) >> kGroupShift;
    const int gsize   = (g == ngroups - 1) ? (grid - (g << kGroupShift))
                                           : kGroupSize;
    unsigned lastflag = 0u;
    const unsigned go = __hip_atomic_fetch_add(
        &counters[g * kCntStride], 1u, __ATOMIC_RELAXED,
        __HIP_MEMORY_SCOPE_AGENT);
    if (go == (unsigned)gsize - 1u) {  // last block of this group
      const unsigned ro = __hip_atomic_fetch_add(
          &counters[kMaxGroups * kCntStride], 1u, __ATOMIC_RELAXED,
          __HIP_MEMORY_SCOPE_AGENT);
      lastflag = (ro == (unsigned)ngroups - 1u) ? 1u : 0u;
    }
    s_last = lastflag;
  }
  __syncthreads();

  // ---------------- winner: deterministic fixed-order reduction ----------
  if (s_last) {
    float v[6] = {0.f, 0.f, 0.f, 0.f, 0.f, 0.f};
    for (int i = tid; i < (int)gridDim.x; i += kThreads) {
#pragma unroll
      for (int k = 0; k < 6; ++k)
        v[k] += __hip_atomic_load(&partials[(size_t)i * 6 + k],
                                  __ATOMIC_RELAXED, __HIP_MEMORY_SCOPE_AGENT);
    }
    const int lane = tid & 63, wid = tid >> 6;
#pragma unroll
    for (int k = 0; k < 6; ++k) {
      const float r = wave_reduce_sum(v[k]);
      if (lane == 0) red[wid][k] = r;
    }
    __syncthreads();
    if (tid == 0) {
      const float S_corr = red[0][0] + red[1][0] + red[2][0] + red[3][0];
      const float S_bbox = red[0][1] + red[1][1] + red[2][1] + red[3][1];
      const float S_dfl  = red[0][2] + red[1][2] + red[2][2] + red[3][2];
      const float S_wt   = red[0][3] + red[1][3] + red[2][3] + red[3][3];
      const float S_pos  = red[0][4] + red[1][4] + red[2][4] + red[3][4];
      const float S_neg  = red[0][5] + red[1][5] + red[2][5] + red[3][5];
      const float num_pos = fmaxf(S_pos, 1.0f);   // num_total_samples
      const float avg     = fmaxf(S_wt, kEps);    // avg_factor = sum(wt)
      out[0] = (S_neg + S_corr) / num_pos
             + 2.0f * S_bbox / avg + 0.0625f * S_dfl / avg;
    }
  }
}

extern "C" void kernel_launch(void* const* d_in, const int* in_sizes, int n_in,
                              void* d_out, int out_size, void* d_ws, size_t ws_size,
                              hipStream_t stream) {
  const float* cls_score     = (const float*)d_in[0];
  const float* bbox_pred     = (const float*)d_in[1];
  const float* anchors       = (const float*)d_in[2];
  const float* bbox_targets  = (const float*)d_in[3];
  const float* label_weights = (const float*)d_in[4];
  const float* strides       = (const float*)d_in[5];
  const int*   labels        = (const int*)d_in[6];
  const int N  = in_sizes[4];      // label_weights is [N]
  const int M4 = N * kF4PerRow;    // float4 count of cls_score

  float*    partials = (float*)d_ws;                          // [grid][6]
  unsigned* counters = (unsigned*)((char*)d_ws +
                        (size_t)kMaxBlocks * 6 * sizeof(float));
  // counters: 32 group lines (128 B apart) + root => (32*32 + 1) uints

  int grid = (M4 + kThreads - 1) / kThreads;
  if (grid > kMaxBlocks) grid = kMaxBlocks;
  if (grid < 1) grid = 1;

  hipMemsetAsync(counters, 0, (kMaxGroups * kCntStride + 1) * sizeof(unsigned),
                 stream);
  nanodet_fused<<<grid, kThreads, 0, stream>>>(
      cls_score, bbox_pred, anchors, bbox_targets, label_weights, strides,
      labels, partials, counters, (float*)d_out, N, M4);
}

// Round 14
// 38.919 us; speedup vs baseline: 1.5805x; 1.3263x over previous
//
#include <hip/hip_runtime.h>

// NanoDet GFL loss (QFL + GIoU + DFL), single f32 scalar output.
// R14 = R11 two-kernel structure (fusion abandoned: R6/R12/R13 all regressed;
// agent-scope arrival + cross-XCD winner reads cost more than a tiny K2)
// with ONE change: phase-1 stream is BLOCK-CONTIGUOUS CHUNKED instead of
// grid-strided. Grid-stride 8-deep gave each block 8 pointers ~8MB apart
// (~16k DRAM stream fronts -> row thrash); chunking gives 1 front per block
// (2048 total), 32KB contiguous per block-iteration.
//   K1: phase 1 = chunked streaming neg-QFL over cls_score (145 MB, f32x4,
//                 8-deep unroll, 4 independent packed accumulators);
//       phase 2 = per-row sparse terms, <=1 row/thread, exec-masked
//                 (lab/lw prefetched before the stream).
//   K2: deterministic fixed-order final reduction + normalization.

namespace {
constexpr int   kNumClasses = 80;
constexpr int   kF4PerRow   = kNumClasses / 4;   // 20
constexpr float kEps        = 1e-6f;
constexpr int   kThreads    = 256;
constexpr int   kMaxBlocks  = 2048;
constexpr float kLog2E      = 1.4426950408889634f;
constexpr float kLn2        = 0.6931471805599453f;
}

typedef __attribute__((ext_vector_type(2))) float f32x2;
typedef __attribute__((ext_vector_type(4))) float f32x4;

__device__ __forceinline__ float fexp2(float x) { return __builtin_amdgcn_exp2f(x); }
__device__ __forceinline__ float flog2(float x) { return __builtin_amdgcn_logf(x); }
__device__ __forceinline__ float frcp(float x)  { return __builtin_amdgcn_rcpf(x); }

__device__ __forceinline__ float wave_reduce_sum(float v) {
#pragma unroll
  for (int off = 32; off > 0; off >>= 1) v += __shfl_down(v, off, 64);
  return v;
}

// Unweighted negative-QFL pair, in log2 units (caller multiplies by ln2):
//   z = e^x; u = 1+z; sig = z/u; returns log2(u) * sig^2 per component.
__device__ __forceinline__ f32x2 neg_t2(f32x2 x) {
  f32x2 t = x * (f32x2)kLog2E;                      // v_pk_mul
  t = __builtin_elementwise_min(t, (f32x2)86.0f);   // overflow guard
  f32x2 z; z.x = fexp2(t.x); z.y = fexp2(t.y);
  const f32x2 u = z + (f32x2)1.0f;                  // v_pk_add
  f32x2 r; r.x = frcp(u.x); r.y = frcp(u.y);
  f32x2 l; l.x = flog2(u.x); l.y = flog2(u.y);
  const f32x2 sig = z * r;                          // v_pk_mul
  return l * sig * sig;                             // 2x v_pk_mul
}

__device__ __forceinline__ f32x2 neg_v4(f32x4 v) {
  f32x2 a; a.x = v.x; a.y = v.y;
  f32x2 b; b.x = v.z; b.y = v.w;
  return neg_t2(a) + neg_t2(b);
}

__device__ __forceinline__ void pos_row_body(
    int n, int lab, float lw,
    const float* __restrict__ cls_score,
    const float* __restrict__ bbox_pred,
    const float* __restrict__ anchors,
    const float* __restrict__ bbox_targets,
    const float* __restrict__ strides,
    float& s_corr, float& s_bbox, float& s_dfl, float& s_wt, float& s_pos)
{
  const bool pos = (unsigned)lab < (unsigned)kNumClasses;
  const bool lwodd = (lw != 1.0f);
  if (!pos && !lwodd) return;  // execz-skips ~95% of lanes

  const float* cr = cls_score + (size_t)n * kNumClasses;
  const f32x4* cr4 = reinterpret_cast<const f32x4*>(cr);

  if (lwodd) {  // never taken for this input; correct for any input
    f32x2 rs = (f32x2)0.0f;
#pragma unroll
    for (int i = 0; i < kF4PerRow; ++i) rs += neg_v4(cr4[i]);
    s_corr = __builtin_fmaf(lw - 1.0f, kLn2 * (rs.x + rs.y), s_corr);
  }

  if (!pos) return;

  const float inv_s = frcp(strides[n]);

  const f32x4 anc = reinterpret_cast<const f32x4*>(anchors)[n];
  const float cx = (anc.x + anc.z) * 0.5f * inv_s;
  const float cy = (anc.y + anc.w) * 0.5f * inv_s;

  const f32x4 tg = reinterpret_cast<const f32x4*>(bbox_targets)[n];
  const float tx0 = tg.x * inv_s, ty0 = tg.y * inv_s;
  const float tx1 = tg.z * inv_s, ty1 = tg.w * inv_s;

  // row max of logits (max sigmoid == sigmoid(max logit))
  float rm = -3.4e38f;
#pragma unroll
  for (int i = 0; i < kF4PerRow; ++i) {
    const f32x4 v = cr4[i];
    rm = fmaxf(rm, fmaxf(fmaxf(v.x, v.y), fmaxf(v.z, v.w)));
  }
  const float em  = fexp2(-fabsf(rm) * kLog2E);
  const float rmr = frcp(1.f + em);
  const float max_sig = (rm >= 0.f) ? rmr : 1.f - rmr;  // == wt

  // fused Integral softmax + DFL per side
  const float dist[4] = {cx - tx0, cy - ty0, tx1 - cx, ty1 - cy};
  float corners[4];
  float dfl = 0.f;
  const float* bp = bbox_pred + (size_t)n * 32;
#pragma unroll
  for (int k = 0; k < 4; ++k) {
    const f32x4 v0 = reinterpret_cast<const f32x4*>(bp)[k * 2 + 0];
    const f32x4 v1 = reinterpret_cast<const f32x4*>(bp)[k * 2 + 1];
    const float xk[8] = {v0.x, v0.y, v0.z, v0.w, v1.x, v1.y, v1.z, v1.w};
    float m = xk[0];
#pragma unroll
    for (int b = 1; b < 8; ++b) m = fmaxf(m, xk[b]);
    const float m2 = m * kLog2E;
    const float d  = fminf(fmaxf(dist[k], 0.f), 6.99f);
    float Z = 0.f, E = 0.f, W = 0.f;
#pragma unroll
    for (int b = 0; b < 8; ++b) {
      const float e = fexp2(__builtin_fmaf(xk[b], kLog2E, -m2));
      Z += e;
      E = __builtin_fmaf((float)b, e, E);
      const float w = fmaxf(1.f - fabsf(d - (float)b), 0.f);
      W = __builtin_fmaf(w, xk[b], W);
    }
    corners[k] = E * frcp(Z);
    dfl += __builtin_fmaf(kLn2, flog2(Z), m) - W;  // logZ_k - W_k
  }

  const float px0 = cx - corners[0], py0 = cy - corners[1];
  const float px1 = cx + corners[2], py1 = cy + corners[3];

  const float ov_w = fmaxf(fminf(px1, tx1) - fmaxf(px0, tx0), 0.f);
  const float ov_h = fmaxf(fminf(py1, ty1) - fmaxf(py0, ty0), 0.f);
  const float overlap = ov_w * ov_h;
  const float area_p = fmaxf(px1 - px0, 0.f) * fmaxf(py1 - py0, 0.f);
  const float area_t = fmaxf(tx1 - tx0, 0.f) * fmaxf(ty1 - ty0, 0.f);
  const float uni = area_p + area_t - overlap;
  const float score = overlap * frcp(fmaxf(uni, kEps));  // aligned IoU

  const float uni_g = fmaxf(uni, kEps);
  const float iou_g = overlap * frcp(uni_g);
  const float en_w = fmaxf(fmaxf(px1, tx1) - fminf(px0, tx0), 0.f);
  const float en_h = fmaxf(fmaxf(py1, ty1) - fminf(py0, ty0), 0.f);
  const float enclose = fmaxf(en_w * en_h, kEps);
  const float giou = iou_g - (enclose - uni_g) * frcp(enclose);

  // QFL positive correction at class `lab` (stable |x| form)
  const float x    = cr[lab];
  const float e    = fexp2(-fabsf(x) * kLog2E);
  const float u    = 1.f + e;
  const float r    = frcp(u);
  const float sig  = (x >= 0.f) ? r : 1.f - r;
  const float bce0 = fmaxf(x, 0.f) + kLn2 * flog2(u);
  const float dq   = score - sig;
  const float corr = (bce0 - x * score) * dq * dq - bce0 * sig * sig;

  s_corr = __builtin_fmaf(corr, lw, s_corr);
  s_bbox = __builtin_fmaf(1.f - giou, max_sig, s_bbox);
  s_dfl  = __builtin_fmaf(dfl, max_sig, s_dfl);
  s_wt  += max_sig;
  s_pos += 1.f;
}

__global__ __launch_bounds__(kThreads) void nanodet_main(
    const float* __restrict__ cls_score,     // [N,80]
    const float* __restrict__ bbox_pred,     // [N,32]
    const float* __restrict__ anchors,       // [N,4]
    const float* __restrict__ bbox_targets,  // [N,4]
    const float* __restrict__ label_weights, // [N]
    const float* __restrict__ strides,       // [N]
    const int*   __restrict__ labels,        // [N]
    float*       __restrict__ partials,      // [grid][6]
    int N, int M4)
{
  const int tid = threadIdx.x;
  const int bid = blockIdx.x;
  const int nth = gridDim.x * kThreads;
  const int n0  = bid * kThreads + tid;

  // Prefetch row predicate data (coalesced) before the stream.
  const int   lab0 = (n0 < N) ? labels[n0] : kNumClasses;
  const float lw0  = (n0 < N) ? label_weights[n0] : 1.0f;

  // -------- phase 1: BLOCK-CONTIGUOUS chunked stream of neg-QFL ----------
  // Each block owns one contiguous slice; 8-deep unroll walks it
  // sequentially (32 KB contiguous per block-iteration, 1 DRAM front/block).
  float s_neg;
  {
    const f32x4* cs = reinterpret_cast<const f32x4*>(cls_score);
    const int chunk = (M4 + (int)gridDim.x - 1) / (int)gridDim.x;
    const int beg = bid * chunk;
    const int end = min(beg + chunk, M4);
    f32x2 a0 = (f32x2)0.f, a1 = (f32x2)0.f, a2 = (f32x2)0.f, a3 = (f32x2)0.f;
    int i = beg + tid;
    for (; i + 7 * kThreads < end; i += 8 * kThreads) {
      const f32x4 v0 = cs[i];
      const f32x4 v1 = cs[i + kThreads];
      const f32x4 v2 = cs[i + 2 * kThreads];
      const f32x4 v3 = cs[i + 3 * kThreads];
      const f32x4 v4 = cs[i + 4 * kThreads];
      const f32x4 v5 = cs[i + 5 * kThreads];
      const f32x4 v6 = cs[i + 6 * kThreads];
      const f32x4 v7 = cs[i + 7 * kThreads];
      a0 += neg_v4(v0); a1 += neg_v4(v1); a2 += neg_v4(v2); a3 += neg_v4(v3);
      a0 += neg_v4(v4); a1 += neg_v4(v5); a2 += neg_v4(v6); a3 += neg_v4(v7);
    }
    for (; i < end; i += kThreads) a0 += neg_v4(cs[i]);
    const f32x2 at = (a0 + a1) + (a2 + a3);
    s_neg = kLn2 * (at.x + at.y);
  }

  // ---------------- phase 2: per-row sparse terms (<=1 row/thread) -------
  float s_corr = 0.f, s_bbox = 0.f, s_dfl = 0.f, s_wt = 0.f, s_pos = 0.f;
  if (n0 < N) {
    pos_row_body(n0, lab0, lw0, cls_score, bbox_pred, anchors, bbox_targets,
                 strides, s_corr, s_bbox, s_dfl, s_wt, s_pos);
  }
  for (int n = n0 + nth; n < N; n += nth) {  // never taken when nth >= N
    pos_row_body(n, labels[n], label_weights[n], cls_score, bbox_pred, anchors,
                 bbox_targets, strides, s_corr, s_bbox, s_dfl, s_wt, s_pos);
  }

  // ---------------- block reduction of 6 sums ----------------
  __shared__ float red[4][6];
  float vals[6] = {s_corr, s_bbox, s_dfl, s_wt, s_pos, s_neg};
  const int lane = tid & 63, wid = tid >> 6;
#pragma unroll
  for (int k = 0; k < 6; ++k) {
    const float r = wave_reduce_sum(vals[k]);
    if (lane == 0) red[wid][k] = r;
  }
  __syncthreads();
  if (tid < 6) {
    const int k = tid;
    partials[(size_t)bid * 6 + k] =
        red[0][k] + red[1][k] + red[2][k] + red[3][k];
  }
}

__global__ __launch_bounds__(kThreads) void nanodet_final(
    const float* __restrict__ partials, int nblocks, float* __restrict__ out)
{
  float v[6] = {0.f, 0.f, 0.f, 0.f, 0.f, 0.f};
  for (int i = threadIdx.x; i < nblocks; i += kThreads) {
#pragma unroll
    for (int k = 0; k < 6; ++k) v[k] += partials[(size_t)i * 6 + k];
  }
  __shared__ float red[4][6];
  const int lane = threadIdx.x & 63, wid = threadIdx.x >> 6;
#pragma unroll
  for (int k = 0; k < 6; ++k) {
    const float r = wave_reduce_sum(v[k]);
    if (lane == 0) red[wid][k] = r;
  }
  __syncthreads();
  if (threadIdx.x == 0) {
    const float S_corr = red[0][0] + red[1][0] + red[2][0] + red[3][0];
    const float S_bbox = red[0][1] + red[1][1] + red[2][1] + red[3][1];
    const float S_dfl  = red[0][2] + red[1][2] + red[2][2] + red[3][2];
    const float S_wt   = red[0][3] + red[1][3] + red[2][3] + red[3][3];
    const float S_pos  = red[0][4] + red[1][4] + red[2][4] + red[3][4];
    const float S_neg  = red[0][5] + red[1][5] + red[2][5] + red[3][5];
    const float num_pos = fmaxf(S_pos, 1.0f);   // num_total_samples
    const float avg     = fmaxf(S_wt, kEps);    // avg_factor = sum(wt)
    out[0] = (S_neg + S_corr) / num_pos
           + 2.0f * S_bbox / avg + 0.0625f * S_dfl / avg;
  }
}

extern "C" void kernel_launch(void* const* d_in, const int* in_sizes, int n_in,
                              void* d_out, int out_size, void* d_ws, size_t ws_size,
                              hipStream_t stream) {
  const float* cls_score     = (const float*)d_in[0];
  const float* bbox_pred     = (const float*)d_in[1];
  const float* anchors       = (const float*)d_in[2];
  const float* bbox_targets  = (const float*)d_in[3];
  const float* label_weights = (const float*)d_in[4];
  const float* strides       = (const float*)d_in[5];
  const int*   labels        = (const int*)d_in[6];
  const int N  = in_sizes[4];      // label_weights is [N]
  const int M4 = N * kF4PerRow;    // float4 count of cls_score

  float* partials = (float*)d_ws;  // [grid][6]

  int grid = (M4 + kThreads - 1) / kThreads;
  if (grid > kMaxBlocks) grid = kMaxBlocks;
  if (grid < 1) grid = 1;

  nanodet_main<<<grid, kThreads, 0, stream>>>(
      cls_score, bbox_pred, anchors, bbox_targets, label_weights, strides,
      labels, partials, N, M4);
  nanodet_final<<<1, kThreads, 0, stream>>>(partials, grid, (float*)d_out);
}